// Round 12
// baseline (54.682 us; speedup 1.0000x reference)
//
#include <hip/hip_runtime.h>

#define SQ 1024
#define DM 1024
#define HD 64
#define NBH 64   // BATCH*NH
#define LOG2E 1.44269504f

typedef __attribute__((ext_vector_type(8))) _Float16 v8h;
typedef __attribute__((ext_vector_type(4))) float v4f;
typedef __attribute__((ext_vector_type(4))) unsigned int v4u;

typedef __attribute__((address_space(3))) void as3_void;
typedef __attribute__((address_space(1))) const void as1_cvoid;

__device__ __forceinline__ v4f mfma_f16(v8h a, v8h b, v4f c) {
  return __builtin_amdgcn_mfma_f32_16x16x32_f16(a, b, c, 0, 0, 0);
}

__device__ __forceinline__ void gload16(const _Float16* g, v8h* l) {
  __builtin_amdgcn_global_load_lds((as1_cvoid*)g, (as3_void*)l, 16, 0, 0);
}

__device__ __forceinline__ float m3(float a, float b, float c) {
  return fmaxf(fmaxf(a, b), c);   // clang fuses to v_max3_f32
}

// Build fp16 Q, K' = (0.125*k + rel_k[s]) * log2e (exp2-domain scores), and
// transposed V'^T where V' = v + rel_v[s].
// Layouts: Qh/Kh: [bh][s][d] (d contiguous, 64), Vth: [bh][d][s] (s contiguous, 1024).
__global__ __launch_bounds__(256) void prep_kernel(
    const float* __restrict__ q, const float* __restrict__ k, const float* __restrict__ v,
    const float* __restrict__ relk, const float* __restrict__ relv,
    _Float16* __restrict__ Qh, _Float16* __restrict__ Kh,
    _Float16* __restrict__ Vth)
{
  __shared__ float vt[64][65];
  int blk = blockIdx.x;            // bh*16 + stile
  int st = blk & 15;
  int bh = blk >> 4;
  int b = bh >> 4, h = bh & 15;
  int s0 = st * 64;
  int t = (int)threadIdx.x;
  int d = t & 63, sl4 = t >> 6;    // 0..3
  const float scale = 0.125f;

  #pragma unroll
  for (int i = 0; i < 16; ++i) {
    int sl = sl4 + i * 4;
    int s = s0 + sl;
    size_t gidx = ((size_t)(b * SQ + s)) * DM + h * HD + d;
    float qv = q[gidx];
    float kv = (k[gidx] * scale + relk[s * HD + d]) * LOG2E;
    float vv = v[gidx] + relv[s * HD + d];
    size_t widx = ((size_t)(bh * SQ + s)) * HD + d;
    Qh[widx] = (_Float16)qv;
    Kh[widx] = (_Float16)kv;
    vt[sl][d] = vv;
  }
  __syncthreads();
  int sl = t & 63, d4 = t >> 6;
  #pragma unroll
  for (int i = 0; i < 16; ++i) {
    int dd = d4 + i * 4;
    Vth[((size_t)(bh * HD + dd)) * SQ + s0 + sl] = (_Float16)vt[sl][dd];
  }
}

// Flash attention fwd. Grid 1024 blocks (XCD-swizzled: 8 XCDs x 128), 4 waves,
// wave owns ONE 16-row q-group. KV tiles of 64, TRIPLE-buffered (48KB LDS),
// staged by global_load_lds (linear LDS dest, XOR swizzle pre-applied on the
// global source granule; same XOR on reads -> conflict-free).
// COUNTED-VMCNT schedule (T3+T4): prologue stages tiles 0,1 (8 loads in
// flight); per iter: s_waitcnt vmcnt(4) [tile t landed, t+1 in flight] ->
// raw s_barrier -> stage(t+2) -> QK -> softmax -> PV. vmcnt never drained to
// 0 in the main loop; NO __syncthreads (no full drain). One barrier/tile.
// Overwrite safety: stage(t+2) targets buf (t-1)%3, whose readers all passed
// the top-of-t barrier. Cross-wave tile-t visibility: each wave's own
// vmcnt(4) wait precedes the barrier. T5 setprio around MFMA clusters.
__global__ __launch_bounds__(256) void attn_kernel(
    const _Float16* __restrict__ Qh, const _Float16* __restrict__ Kh,
    const _Float16* __restrict__ Vth, float* __restrict__ out)
{
  __shared__ v8h KlG[3 * 512];   // K' tiles  [krow][d]  3 x 8KB
  __shared__ v8h VlG[3 * 512];   // V'^T tiles [d][kcol] 3 x 8KB

  int tid = (int)threadIdx.x;
  int lane = tid & 63, w = tid >> 6;
  int g = lane >> 4, r15 = lane & 15;
  // bijective XCD swizzle: 1024 = 8 XCDs x 128; each XCD gets 8 whole bh (2MB KV < 4MB L2)
  int bid = (int)blockIdx.x;
  int wk = (bid & 7) * 128 + (bid >> 3);
  int bh = wk >> 4, qt = wk & 15;
  int b = bh >> 4, h = bh & 15;
  int q0 = qt * 64 + w * 16;

  // Q B-frag: col = q = r15, contraction d = 8g+j (+32 for [1])
  const _Float16* qb = Qh + ((size_t)(bh * SQ + q0 + r15)) * HD;
  v8h aq0 = *(const v8h*)(qb + g * 8);
  v8h aq1 = *(const v8h*)(qb + 32 + g * 8);

  const _Float16* kb = Kh + (size_t)bh * SQ * HD;
  const _Float16* vb = Vth + (size_t)bh * HD * SQ;

  // staging precompute: LDS granule G = w*128 + j*64 + lane (linear dest,
  // HW adds lane*16), source granule = (row, gr ^ f(row)) of the logical tile
  size_t kOff[2], vOff[2];
  int ldsG[2];
  #pragma unroll
  for (int j = 0; j < 2; ++j) {
    int G = w * 128 + j * 64 + lane;
    int row = G >> 3, gr = G & 7;
    int fs = (row & 3) | (((row >> 3) & 1) << 2);
    int src = gr ^ fs;
    kOff[j] = (size_t)row * HD + src * 8;
    vOff[j] = (size_t)row * SQ + src * 8;
    ldsG[j] = w * 128 + j * 64;
  }

  v4f o[4];
  #pragma unroll
  for (int c = 0; c < 4; ++c) o[c] = (v4f){0.f, 0.f, 0.f, 0.f};
  float m = -3.0e38f, l = 0.f;

  // K-frag read rows (permuted): k_phys(c,mm) = 32*(c>>1) + 8*(mm>>2) + 4*(c&1) + (mm&3)
  int krow[4];
  #pragma unroll
  for (int c = 0; c < 4; ++c)
    krow[c] = ((c >> 1) << 5) + ((r15 >> 2) << 3) + ((c & 1) << 2) + (r15 & 3);
  int fk = (r15 & 3) | (((r15 >> 2) & 1) << 2);   // f(krow[c]) for all c
  int fv = (r15 & 3) | (((r15 >> 3) & 1) << 2);   // f(16c + r15) for all c

  const int NT = SQ / 64;

  // ---- prologue: stage tiles 0 and 1 (8 loads in flight, NO drain) ----
  #pragma unroll
  for (int j = 0; j < 2; ++j) {
    gload16(kb + kOff[j], &KlG[ldsG[j]]);
    gload16(vb + vOff[j], &VlG[ldsG[j]]);
  }
  #pragma unroll
  for (int j = 0; j < 2; ++j) {
    gload16(kb + (size_t)64 * HD + kOff[j], &KlG[512 + ldsG[j]]);
    gload16(vb + 64 + vOff[j], &VlG[512 + ldsG[j]]);
  }

  int cur = 0;   // rotating buffer index t0 % 3
  for (int t0 = 0; t0 < NT; ++t0) {
    // ---- counted wait: tile t0's 4 loads landed; t0+1's may stay in flight ----
    if (t0 == NT - 1) {
      asm volatile("s_waitcnt vmcnt(0)" ::: "memory");
    } else {
      asm volatile("s_waitcnt vmcnt(4)" ::: "memory");
    }
    __builtin_amdgcn_s_barrier();   // raw barrier: no vmcnt/lgkm drain

    // ---- issue stage(t0+2) into buf (t0+2)%3 = (t0-1)%3 (readers done) ----
    if (t0 + 2 < NT) {
      int bstage = (cur + 2 >= 3) ? cur - 1 : cur + 2;
      size_t kT = (size_t)(t0 + 2) * 64 * HD;
      size_t vT = (size_t)(t0 + 2) * 64;
      #pragma unroll
      for (int j = 0; j < 2; ++j) {
        gload16(kb + kT + kOff[j], &KlG[bstage * 512 + ldsG[j]]);
        gload16(vb + vT + vOff[j], &VlG[bstage * 512 + ldsG[j]]);
      }
    }

    // ---- S^T = K'.Q^T : s[c][r] = S2[q=r15][k_phys(c,4g+r)] (exp2 domain) ----
    v4f s[4];
    __builtin_amdgcn_s_setprio(1);
    #pragma unroll
    for (int c = 0; c < 4; ++c) {
      v8h kf0 = KlG[cur * 512 + krow[c] * 8 + (g ^ fk)];
      v8h kf1 = KlG[cur * 512 + krow[c] * 8 + ((4 | g) ^ fk)];
      v4f z = (v4f){0.f, 0.f, 0.f, 0.f};
      z = mfma_f16(kf0, aq0, z);
      z = mfma_f16(kf1, aq1, z);
      s[c] = z;
    }
    __builtin_amdgcn_s_setprio(0);

    // ---- exp2-domain online softmax, defer-max (T13, THR=8) ----
    float pa = m3(s[0][0], s[0][1], s[0][2]);
    float pb = m3(s[0][3], s[1][0], s[1][1]);
    float pc = m3(s[1][2], s[1][3], s[2][0]);
    float pd = m3(s[2][1], s[2][2], s[2][3]);
    float pe = m3(s[3][0], s[3][1], s[3][2]);
    float pm = m3(fmaxf(pa, pb), fmaxf(pc, pd), fmaxf(pe, s[3][3]));
    if (!__all(pm - m <= 8.f)) {
      float pmr = fmaxf(pm, __shfl_xor(pm, 16));
      pmr = fmaxf(pmr, __shfl_xor(pmr, 32));
      float mnew = fmaxf(m, pmr);
      float sc = __builtin_amdgcn_exp2f(m - mnew);
      m = mnew;
      l *= sc;
      #pragma unroll
      for (int c = 0; c < 4; ++c) o[c] *= sc;
    }
    float p[16];
    #pragma unroll
    for (int c = 0; c < 4; ++c)
      #pragma unroll
      for (int r = 0; r < 4; ++r) {
        float pv = __builtin_amdgcn_exp2f(s[c][r] - m);
        s[c][r] = pv;
        p[c * 4 + r] = pv;
      }
    float s0 = (p[0] + p[1]) + (p[2] + p[3]);
    float s1 = (p[4] + p[5]) + (p[6] + p[7]);
    float s2 = (p[8] + p[9]) + (p[10] + p[11]);
    float s3 = (p[12] + p[13]) + (p[14] + p[15]);
    l += (s0 + s1) + (s2 + s3);

    // ---- pack P in-lane: acc IS the PV B-frag layout (k-slot 8g+j / 32+8g+j) ----
    v4u w0, w1;
    w0[0] = __builtin_bit_cast(unsigned int, __builtin_amdgcn_cvt_pkrtz(s[0][0], s[0][1]));
    w0[1] = __builtin_bit_cast(unsigned int, __builtin_amdgcn_cvt_pkrtz(s[0][2], s[0][3]));
    w0[2] = __builtin_bit_cast(unsigned int, __builtin_amdgcn_cvt_pkrtz(s[1][0], s[1][1]));
    w0[3] = __builtin_bit_cast(unsigned int, __builtin_amdgcn_cvt_pkrtz(s[1][2], s[1][3]));
    w1[0] = __builtin_bit_cast(unsigned int, __builtin_amdgcn_cvt_pkrtz(s[2][0], s[2][1]));
    w1[1] = __builtin_bit_cast(unsigned int, __builtin_amdgcn_cvt_pkrtz(s[2][2], s[2][3]));
    w1[2] = __builtin_bit_cast(unsigned int, __builtin_amdgcn_cvt_pkrtz(s[3][0], s[3][1]));
    w1[3] = __builtin_bit_cast(unsigned int, __builtin_amdgcn_cvt_pkrtz(s[3][2], s[3][3]));
    v8h pb0 = __builtin_bit_cast(v8h, w0);
    v8h pb1 = __builtin_bit_cast(v8h, w1);

    // ---- O^T += V'^T . P ----
    __builtin_amdgcn_s_setprio(1);
    #pragma unroll
    for (int c = 0; c < 4; ++c) {
      int rv = 16 * c + r15;
      v8h vf0 = VlG[cur * 512 + rv * 8 + (g ^ fv)];
      v8h vf1 = VlG[cur * 512 + rv * 8 + ((4 | g) ^ fv)];
      o[c] = mfma_f16(vf0, pb0, o[c]);
      o[c] = mfma_f16(vf1, pb1, o[c]);
    }
    __builtin_amdgcn_s_setprio(0);

    cur = (cur + 1 >= 3) ? 0 : cur + 1;
    // no end barrier: next iteration's top waitcnt+barrier is the tile boundary
  }

  // ---- epilogue: reduce l across k-chunk lanes, normalize, vectorized stores ----
  float lr = l;
  lr += __shfl_xor(lr, 16);
  lr += __shfl_xor(lr, 32);
  float inv = 1.f / lr;
  int qrow = q0 + r15;
  #pragma unroll
  for (int c = 0; c < 4; ++c) {
    v4f res = o[c] * inv;
    *(v4f*)(&out[((size_t)(b * SQ + qrow)) * DM + h * HD + 16 * c + 4 * g]) = res;
  }
}

extern "C" void kernel_launch(void* const* d_in, const int* in_sizes, int n_in,
                              void* d_out, int out_size, void* d_ws, size_t ws_size,
                              hipStream_t stream) {
  const float* q = (const float*)d_in[0];
  const float* k = (const float*)d_in[1];
  const float* v = (const float*)d_in[2];
  const float* relk = (const float*)d_in[3];
  const float* relv = (const float*)d_in[4];

  _Float16* Qh = (_Float16*)d_ws;
  _Float16* Kh = Qh + (size_t)NBH * SQ * HD;
  _Float16* Vth = Kh + (size_t)NBH * SQ * HD;

  prep_kernel<<<dim3(NBH * (SQ / 64)), dim3(256), 0, stream>>>(q, k, v, relk, relv, Qh, Kh, Vth);
  attn_kernel<<<dim3(1024), dim3(256), 0, stream>>>(Qh, Kh, Vth, (float*)d_out);
}

// Round 13
// 52.396 us; speedup vs baseline: 1.0436x; 1.0436x over previous
//
#include <hip/hip_runtime.h>

#define SQ 1024
#define DM 1024
#define HD 64
#define NBH 64   // BATCH*NH
#define LOG2E 1.44269504f

typedef __attribute__((ext_vector_type(8))) _Float16 v8h;
typedef __attribute__((ext_vector_type(4))) float v4f;
typedef __attribute__((ext_vector_type(16))) float v16f;
typedef __attribute__((ext_vector_type(4))) unsigned int v4u;

typedef __attribute__((address_space(3))) void as3_void;
typedef __attribute__((address_space(1))) const void as1_cvoid;

__device__ __forceinline__ v16f mfma32(v8h a, v8h b, v16f c) {
  return __builtin_amdgcn_mfma_f32_32x32x16_f16(a, b, c, 0, 0, 0);
}

__device__ __forceinline__ void gload16(const _Float16* g, v8h* l) {
  __builtin_amdgcn_global_load_lds((as1_cvoid*)g, (as3_void*)l, 16, 0, 0);
}

// Build fp16 Q, K' = (0.125*k + rel_k[s]) * log2e (exp2-domain scores), and
// transposed V'^T where V' = v + rel_v[s], with k-index bits 2<->3 SWAPPED in
// storage (so the 32x32 PV B-slot permutation reads contiguous b128).
// Layouts: Qh/Kh: [bh][s][d] (d contiguous, 64), Vth: [bh][d][k_stored].
__global__ __launch_bounds__(256) void prep_kernel(
    const float* __restrict__ q, const float* __restrict__ k, const float* __restrict__ v,
    const float* __restrict__ relk, const float* __restrict__ relv,
    _Float16* __restrict__ Qh, _Float16* __restrict__ Kh,
    _Float16* __restrict__ Vth)
{
  __shared__ float vt[64][65];
  int blk = blockIdx.x;            // bh*16 + stile
  int st = blk & 15;
  int bh = blk >> 4;
  int b = bh >> 4, h = bh & 15;
  int s0 = st * 64;
  int t = (int)threadIdx.x;
  int d = t & 63, sl4 = t >> 6;    // 0..3
  const float scale = 0.125f;

  #pragma unroll
  for (int i = 0; i < 16; ++i) {
    int sl = sl4 + i * 4;
    int s = s0 + sl;
    size_t gidx = ((size_t)(b * SQ + s)) * DM + h * HD + d;
    float qv = q[gidx];
    float kv = (k[gidx] * scale + relk[s * HD + d]) * LOG2E;
    float vv = v[gidx] + relv[s * HD + d];
    size_t widx = ((size_t)(bh * SQ + s)) * HD + d;
    Qh[widx] = (_Float16)qv;
    Kh[widx] = (_Float16)kv;
    vt[sl][d] = vv;
  }
  __syncthreads();
  int sl = t & 63, d4 = t >> 6;
  int swp = (sl & 51) | ((sl & 4) << 1) | ((sl & 8) >> 1);   // swap bits 2,3
  #pragma unroll
  for (int i = 0; i < 16; ++i) {
    int dd = d4 + i * 4;
    Vth[((size_t)(bh * HD + dd)) * SQ + s0 + swp] = (_Float16)vt[sl][dd];
  }
}

// Flash attention fwd, 32x32x16 MFMA. Grid 1024 blocks (XCD-swizzled), 128 thr
// = 2 waves, wave owns 32 q-rows (q = lane&31; halves hold disjoint key sets).
// KV tiles of 64, double-buffered (32KB -> exactly 4 blocks/CU, no tail),
// staged via global_load_lds (linear LDS dest, XOR swizzle pre-applied on the
// global source granule; same XOR on reads).
// QK^T swapped: S^T[key][q]; C/D layout puts 32 scores/lane ALL FOR ONE q ->
// softmax fully lane-local (shuffles only in rare rescale + epilogue).
// Score-reg k-set per lane == PV B-operand slot k-set per half (derivation in
// round notes), so P-pack is 16 in-lane cvt_pkrtz. V stored k-bit-swapped so
// PV A-frags are contiguous b128.
__global__ __launch_bounds__(128) void attn_kernel(
    const _Float16* __restrict__ Qh, const _Float16* __restrict__ Kh,
    const _Float16* __restrict__ Vth, float* __restrict__ out)
{
  __shared__ v8h KlG[2 * 512];   // K' [key][hd-granule^XOR] x2 buf, 16KB
  __shared__ v8h VlG[2 * 512];   // V'^T [d][k_stored-granule^XOR] x2 buf, 16KB

  int tid = (int)threadIdx.x;
  int lane = tid & 63, w = tid >> 6;       // w = 0,1
  int q31 = lane & 31, half = lane >> 5;
  // bijective XCD swizzle: 1024 = 8 XCDs x 128; each XCD gets 8 whole bh
  int bid = (int)blockIdx.x;
  int wk = (bid & 7) * 128 + (bid >> 3);
  int bh = wk >> 4, qt = wk & 15;
  int b = bh >> 4, h = bh & 15;
  int qrow = qt * 64 + w * 32 + q31;

  // Q B-frags: aq[cc] = Qh[bh][qrow][16cc + 8*half + j], j=0..7
  const _Float16* qb = Qh + ((size_t)(bh * SQ + qrow)) * HD + 8 * half;
  v8h aq[4];
  #pragma unroll
  for (int cc = 0; cc < 4; ++cc) aq[cc] = *(const v8h*)(qb + 16 * cc);

  const _Float16* kb = Kh + (size_t)bh * SQ * HD;
  const _Float16* vb = Vth + (size_t)bh * HD * SQ;

  // staging: per wave 4 K-gloads + 4 V-gloads per tile.
  // LDS granule G = (w*64 + i*128) + lane (linear dest; HW adds lane*16B);
  // logical tile granule (row, gr): row = G>>3, gr = G&7; source pre-XOR'd.
  size_t kOff[4], vOff[4];
  int ldsG[4];
  #pragma unroll
  for (int i = 0; i < 4; ++i) {
    int G = w * 64 + i * 128 + lane;
    int row = G >> 3, gr = G & 7;
    int src = gr ^ (row & 7);
    kOff[i] = (size_t)row * HD + src * 8;
    vOff[i] = (size_t)row * SQ + src * 8;
    ldsG[i] = w * 64 + i * 128;
  }

  v16f o0 = {0.f,0.f,0.f,0.f,0.f,0.f,0.f,0.f,0.f,0.f,0.f,0.f,0.f,0.f,0.f,0.f};
  v16f o1 = o0;
  float m = -3.0e38f, l = 0.f;

  // ds_read granule XOR for compute reads: row&7 == q31&7 for all chunks
  int rx = q31 & 7;

  const int NT = SQ / 64;

  // ---- prologue: stage tile 0 ----
  #pragma unroll
  for (int i = 0; i < 4; ++i) {
    gload16(kb + kOff[i], &KlG[ldsG[i]]);
    gload16(vb + vOff[i], &VlG[ldsG[i]]);
  }
  __syncthreads();

  for (int t0 = 0; t0 < NT; ++t0) {
    int cur = t0 & 1;
    // ---- issue next tile's loads into the other buffer ----
    if (t0 < NT - 1) {
      size_t kT = (size_t)(t0 + 1) * 64 * HD;
      size_t vT = (size_t)(t0 + 1) * 64;
      #pragma unroll
      for (int i = 0; i < 4; ++i) {
        gload16(kb + kT + kOff[i], &KlG[(cur ^ 1) * 512 + ldsG[i]]);
        gload16(vb + vT + vOff[i], &VlG[(cur ^ 1) * 512 + ldsG[i]]);
      }
    }

    // ---- S^T = K'.Q^T : per key-chunk kc, 4 chained hd-MFMAs ----
    // score s[kc][reg] = S2[key = 32kc + (reg&3)+8*(reg>>2)+4*half][q=q31]
    v16f s0v = o0 * 0.f;   // zeros
    v16f s1v = s0v;
    #pragma unroll
    for (int cc = 0; cc < 4; ++cc) {
      v8h kf0 = KlG[cur * 512 + (q31) * 8 + ((2 * cc + half) ^ rx)];
      v8h kf1 = KlG[cur * 512 + (32 + q31) * 8 + ((2 * cc + half) ^ rx)];
      s0v = mfma32(kf0, aq[cc], s0v);
      s1v = mfma32(kf1, aq[cc], s1v);
    }

    // ---- lane-local softmax over 32 scores (exp2 domain, defer-max T13) ----
    float sc32[32];
    #pragma unroll
    for (int r = 0; r < 16; ++r) { sc32[r] = s0v[r]; sc32[16 + r] = s1v[r]; }
    float mx[16];
    #pragma unroll
    for (int r = 0; r < 16; ++r) mx[r] = fmaxf(sc32[2 * r], sc32[2 * r + 1]);
    #pragma unroll
    for (int r = 0; r < 8; ++r) mx[r] = fmaxf(mx[r], mx[r + 8]);
    #pragma unroll
    for (int r = 0; r < 4; ++r) mx[r] = fmaxf(mx[r], mx[r + 4]);
    float pm = fmaxf(fmaxf(mx[0], mx[1]), fmaxf(mx[2], mx[3]));
    if (!__all(pm - m <= 8.f)) {
      float pmr = fmaxf(pm, __shfl_xor(pm, 32));
      float mnew = fmaxf(m, pmr);
      float sc = __builtin_amdgcn_exp2f(m - mnew);
      m = mnew;
      l *= sc;
      o0 *= sc;
      o1 *= sc;
    }
    #pragma unroll
    for (int r = 0; r < 32; ++r)
      sc32[r] = __builtin_amdgcn_exp2f(sc32[r] - m);
    float ad[16];
    #pragma unroll
    for (int r = 0; r < 16; ++r) ad[r] = sc32[2 * r] + sc32[2 * r + 1];
    #pragma unroll
    for (int r = 0; r < 8; ++r) ad[r] += ad[r + 8];
    #pragma unroll
    for (int r = 0; r < 4; ++r) ad[r] += ad[r + 4];
    l += (ad[0] + ad[1]) + (ad[2] + ad[3]);

    // ---- pack P in-lane: pb[c] covers PV k-chunk c (16 keys) ----
    // B slot (j, half) needs k = 16c + 4*half + 8*(j>>2) + (j&3)
    //   == score reg sc32[8c + j]  (exact match, derived)
    v8h pb[4];
    #pragma unroll
    for (int c = 0; c < 4; ++c) {
      v4u wds;
      #pragma unroll
      for (int r = 0; r < 4; ++r)
        wds[r] = __builtin_bit_cast(unsigned int,
                   __builtin_amdgcn_cvt_pkrtz(sc32[c * 8 + 2 * r], sc32[c * 8 + 2 * r + 1]));
      pb[c] = __builtin_bit_cast(v8h, wds);
    }

    // ---- O^T += V'^T . P : 2 d-chunks x 4 k-chunks ----
    #pragma unroll
    for (int c = 0; c < 4; ++c) {
      v8h vf0 = VlG[cur * 512 + (q31) * 8 + ((2 * c + half) ^ rx)];
      v8h vf1 = VlG[cur * 512 + (32 + q31) * 8 + ((2 * c + half) ^ rx)];
      o0 = mfma32(vf0, pb[c], o0);
      o1 = mfma32(vf1, pb[c], o1);
    }

    __syncthreads();   // tile boundary: buffer swap safety + staging drain
  }

  // ---- epilogue: merge l across the half-pair, normalize, store ----
  float lr = l + __shfl_xor(l, 32);
  float inv = 1.f / lr;
  float* ob = out + ((size_t)(b * SQ + qrow)) * DM + h * HD;
  #pragma unroll
  for (int rq = 0; rq < 4; ++rq) {
    v4f r0, r1;
    #pragma unroll
    for (int j = 0; j < 4; ++j) {
      r0[j] = o0[4 * rq + j] * inv;
      r1[j] = o1[4 * rq + j] * inv;
    }
    int d0 = 8 * rq + 4 * half;
    *(v4f*)(ob + d0) = r0;
    *(v4f*)(ob + 32 + d0) = r1;
  }
}

extern "C" void kernel_launch(void* const* d_in, const int* in_sizes, int n_in,
                              void* d_out, int out_size, void* d_ws, size_t ws_size,
                              hipStream_t stream) {
  const float* q = (const float*)d_in[0];
  const float* k = (const float*)d_in[1];
  const float* v = (const float*)d_in[2];
  const float* relk = (const float*)d_in[3];
  const float* relv = (const float*)d_in[4];

  _Float16* Qh = (_Float16*)d_ws;
  _Float16* Kh = Qh + (size_t)NBH * SQ * HD;
  _Float16* Vth = Kh + (size_t)NBH * SQ * HD;

  prep_kernel<<<dim3(NBH * (SQ / 64)), dim3(256), 0, stream>>>(q, k, v, relk, relv, Qh, Kh, Vth);
  attn_kernel<<<dim3(1024), dim3(128), 0, stream>>>(Qh, Kh, Vth, (float*)d_out);
}

// Round 14
// 49.545 us; speedup vs baseline: 1.1037x; 1.0576x over previous
//
#include <hip/hip_runtime.h>

#define SQ 1024
#define DM 1024
#define HD 64
#define NBH 64   // BATCH*NH
#define LOG2E 1.44269504f

typedef __attribute__((ext_vector_type(8))) _Float16 v8h;
typedef __attribute__((ext_vector_type(4))) float v4f;
typedef __attribute__((ext_vector_type(4))) unsigned int v4u;

typedef __attribute__((address_space(3))) void as3_void;
typedef __attribute__((address_space(1))) const void as1_cvoid;

__device__ __forceinline__ v4f mfma_f16(v8h a, v8h b, v4f c) {
  return __builtin_amdgcn_mfma_f32_16x16x32_f16(a, b, c, 0, 0, 0);
}

__device__ __forceinline__ void gload16(const _Float16* g, v8h* l) {
  __builtin_amdgcn_global_load_lds((as1_cvoid*)g, (as3_void*)l, 16, 0, 0);
}

__device__ __forceinline__ float m3(float a, float b, float c) {
  return fmaxf(fmaxf(a, b), c);   // clang fuses to v_max3_f32
}

// Build fp16 Q, K' = (0.125*k + rel_k[s]) * log2e (exp2-domain scores), and
// transposed V'^T where V' = v + rel_v[s].
// Layouts: Qh/Kh: [bh][s][d] (d contiguous, 64), Vth: [bh][d][s] (s contiguous, 1024).
__global__ __launch_bounds__(256) void prep_kernel(
    const float* __restrict__ q, const float* __restrict__ k, const float* __restrict__ v,
    const float* __restrict__ relk, const float* __restrict__ relv,
    _Float16* __restrict__ Qh, _Float16* __restrict__ Kh,
    _Float16* __restrict__ Vth)
{
  __shared__ float vt[64][65];
  int blk = blockIdx.x;            // bh*16 + stile
  int st = blk & 15;
  int bh = blk >> 4;
  int b = bh >> 4, h = bh & 15;
  int s0 = st * 64;
  int t = (int)threadIdx.x;
  int d = t & 63, sl4 = t >> 6;    // 0..3
  const float scale = 0.125f;

  #pragma unroll
  for (int i = 0; i < 16; ++i) {
    int sl = sl4 + i * 4;
    int s = s0 + sl;
    size_t gidx = ((size_t)(b * SQ + s)) * DM + h * HD + d;
    float qv = q[gidx];
    float kv = (k[gidx] * scale + relk[s * HD + d]) * LOG2E;
    float vv = v[gidx] + relv[s * HD + d];
    size_t widx = ((size_t)(bh * SQ + s)) * HD + d;
    Qh[widx] = (_Float16)qv;
    Kh[widx] = (_Float16)kv;
    vt[sl][d] = vv;
  }
  __syncthreads();
  int sl = t & 63, d4 = t >> 6;
  #pragma unroll
  for (int i = 0; i < 16; ++i) {
    int dd = d4 + i * 4;
    Vth[((size_t)(bh * HD + dd)) * SQ + s0 + sl] = (_Float16)vt[sl][dd];
  }
}

// Flash attention fwd — r10 structure with the main loop FULLY UNROLLED so all
// LDS addresses are compile-time literals (hoisted / offset-immediates) and
// per-tile address bookkeeping VALU vanishes.
// Grid 1024 blocks (XCD-swizzled: 8 XCDs x 128), 4 waves, wave owns ONE
// 16-row q-group. KV tiles of 64, double-buffered (32KB -> 4 blocks/CU),
// staged by global_load_lds (linear LDS dest, XOR swizzle pre-applied on the
// global source granule; same XOR on reads -> conflict-free). 2-phase:
// stage(t+1) issued before compute(t), one __syncthreads per tile.
// QK^T: S^T = K'.Q^T with permuted A-rows -> acc already in PV B-frag layout.
// Scores exp2-domain (LOG2E folded into K' at prep).
__global__ __launch_bounds__(256) void attn_kernel(
    const _Float16* __restrict__ Qh, const _Float16* __restrict__ Kh,
    const _Float16* __restrict__ Vth, float* __restrict__ out)
{
  __shared__ v8h KlG[2 * 512];   // K' tiles  [krow][d]  2 x 8KB
  __shared__ v8h VlG[2 * 512];   // V'^T tiles [d][kcol] 2 x 8KB

  int tid = (int)threadIdx.x;
  int lane = tid & 63, w = tid >> 6;
  int g = lane >> 4, r15 = lane & 15;
  // bijective XCD swizzle: 1024 = 8 XCDs x 128; each XCD gets 8 whole bh (2MB KV < 4MB L2)
  int bid = (int)blockIdx.x;
  int wk = (bid & 7) * 128 + (bid >> 3);
  int bh = wk >> 4, qt = wk & 15;
  int b = bh >> 4, h = bh & 15;
  int q0 = qt * 64 + w * 16;

  // Q B-frag: col = q = r15, contraction d = 8g+j (+32 for [1])
  const _Float16* qb = Qh + ((size_t)(bh * SQ + q0 + r15)) * HD;
  v8h aq0 = *(const v8h*)(qb + g * 8);
  v8h aq1 = *(const v8h*)(qb + 32 + g * 8);

  const _Float16* kb = Kh + (size_t)bh * SQ * HD;
  const _Float16* vb = Vth + (size_t)bh * HD * SQ;

  // staging precompute: LDS granule G = w*128 + j*64 + lane (linear dest,
  // HW adds lane*16), source granule = (row, gr ^ f(row)) of the logical tile
  size_t kOff[2], vOff[2];
  int ldsG[2];
  #pragma unroll
  for (int j = 0; j < 2; ++j) {
    int G = w * 128 + j * 64 + lane;
    int row = G >> 3, gr = G & 7;
    int fs = (row & 3) | (((row >> 3) & 1) << 2);
    int src = gr ^ fs;
    kOff[j] = (size_t)row * HD + src * 8;
    vOff[j] = (size_t)row * SQ + src * 8;
    ldsG[j] = w * 128 + j * 64;
  }

  v4f o[4];
  #pragma unroll
  for (int c = 0; c < 4; ++c) o[c] = (v4f){0.f, 0.f, 0.f, 0.f};
  float m = -3.0e38f, l = 0.f;

  // K-frag read rows (permuted): k_phys(c,mm) = 32*(c>>1) + 8*(mm>>2) + 4*(c&1) + (mm&3)
  int krow[4];
  #pragma unroll
  for (int c = 0; c < 4; ++c)
    krow[c] = ((c >> 1) << 5) + ((r15 >> 2) << 3) + ((c & 1) << 2) + (r15 & 3);
  int fk = (r15 & 3) | (((r15 >> 2) & 1) << 2);   // f(krow[c]) for all c
  int fv = (r15 & 3) | (((r15 >> 3) & 1) << 2);   // f(16c + r15) for all c

  const int NT = SQ / 64;

  // ---- prologue: stage tile 0 ----
  #pragma unroll
  for (int j = 0; j < 2; ++j) {
    gload16(kb + kOff[j], &KlG[ldsG[j]]);
    gload16(vb + vOff[j], &VlG[ldsG[j]]);
  }
  __syncthreads();   // drains vmcnt(0): tile 0 resident

  #pragma unroll
  for (int t0 = 0; t0 < NT; ++t0) {
    const int cur = t0 & 1;   // literal after unroll
    // ---- issue next tile's loads into the other buffer ----
    if (t0 < NT - 1) {
      size_t kT = (size_t)(t0 + 1) * 64 * HD;
      size_t vT = (size_t)(t0 + 1) * 64;
      #pragma unroll
      for (int j = 0; j < 2; ++j) {
        gload16(kb + kT + kOff[j], &KlG[(cur ^ 1) * 512 + ldsG[j]]);
        gload16(vb + vT + vOff[j], &VlG[(cur ^ 1) * 512 + ldsG[j]]);
      }
    }

    // ---- S^T = K'.Q^T : s[c][r] = S2[q=r15][k_phys(c,4g+r)] (exp2 domain) ----
    v4f s[4];
    #pragma unroll
    for (int c = 0; c < 4; ++c) {
      v8h kf0 = KlG[cur * 512 + krow[c] * 8 + (g ^ fk)];
      v8h kf1 = KlG[cur * 512 + krow[c] * 8 + ((4 | g) ^ fk)];
      v4f z = (v4f){0.f, 0.f, 0.f, 0.f};
      z = mfma_f16(kf0, aq0, z);
      z = mfma_f16(kf1, aq1, z);
      s[c] = z;
    }

    // ---- exp2-domain online softmax, defer-max (T13, THR=8) ----
    float pa = m3(s[0][0], s[0][1], s[0][2]);
    float pb = m3(s[0][3], s[1][0], s[1][1]);
    float pc = m3(s[1][2], s[1][3], s[2][0]);
    float pd = m3(s[2][1], s[2][2], s[2][3]);
    float pe = m3(s[3][0], s[3][1], s[3][2]);
    float pm = m3(fmaxf(pa, pb), fmaxf(pc, pd), fmaxf(pe, s[3][3]));
    if (!__all(pm - m <= 8.f)) {
      float pmr = fmaxf(pm, __shfl_xor(pm, 16));
      pmr = fmaxf(pmr, __shfl_xor(pmr, 32));
      float mnew = fmaxf(m, pmr);
      float sc = __builtin_amdgcn_exp2f(m - mnew);
      m = mnew;
      l *= sc;
      #pragma unroll
      for (int c = 0; c < 4; ++c) o[c] *= sc;
    }
    float p[16];
    #pragma unroll
    for (int c = 0; c < 4; ++c)
      #pragma unroll
      for (int r = 0; r < 4; ++r) {
        float pv = __builtin_amdgcn_exp2f(s[c][r] - m);
        s[c][r] = pv;
        p[c * 4 + r] = pv;
      }
    float s0 = (p[0] + p[1]) + (p[2] + p[3]);
    float s1 = (p[4] + p[5]) + (p[6] + p[7]);
    float s2 = (p[8] + p[9]) + (p[10] + p[11]);
    float s3 = (p[12] + p[13]) + (p[14] + p[15]);
    l += (s0 + s1) + (s2 + s3);

    // ---- pack P in-lane: acc IS the PV B-frag layout (k-slot 8g+j / 32+8g+j) ----
    v4u w0, w1;
    w0[0] = __builtin_bit_cast(unsigned int, __builtin_amdgcn_cvt_pkrtz(s[0][0], s[0][1]));
    w0[1] = __builtin_bit_cast(unsigned int, __builtin_amdgcn_cvt_pkrtz(s[0][2], s[0][3]));
    w0[2] = __builtin_bit_cast(unsigned int, __builtin_amdgcn_cvt_pkrtz(s[1][0], s[1][1]));
    w0[3] = __builtin_bit_cast(unsigned int, __builtin_amdgcn_cvt_pkrtz(s[1][2], s[1][3]));
    w1[0] = __builtin_bit_cast(unsigned int, __builtin_amdgcn_cvt_pkrtz(s[2][0], s[2][1]));
    w1[1] = __builtin_bit_cast(unsigned int, __builtin_amdgcn_cvt_pkrtz(s[2][2], s[2][3]));
    w1[2] = __builtin_bit_cast(unsigned int, __builtin_amdgcn_cvt_pkrtz(s[3][0], s[3][1]));
    w1[3] = __builtin_bit_cast(unsigned int, __builtin_amdgcn_cvt_pkrtz(s[3][2], s[3][3]));
    v8h pb0 = __builtin_bit_cast(v8h, w0);
    v8h pb1 = __builtin_bit_cast(v8h, w1);

    // ---- O^T += V'^T . P ----
    #pragma unroll
    for (int c = 0; c < 4; ++c) {
      int rv = 16 * c + r15;
      v8h vf0 = VlG[cur * 512 + rv * 8 + (g ^ fv)];
      v8h vf1 = VlG[cur * 512 + rv * 8 + ((4 | g) ^ fv)];
      o[c] = mfma_f16(vf0, pb0, o[c]);
      o[c] = mfma_f16(vf1, pb1, o[c]);
    }

    __syncthreads();   // tile boundary: buffer swap safety + staging drain
  }

  // ---- epilogue: reduce l across k-chunk lanes, normalize, vectorized stores ----
  float lr = l;
  lr += __shfl_xor(lr, 16);
  lr += __shfl_xor(lr, 32);
  float inv = 1.f / lr;
  int qrow = q0 + r15;
  #pragma unroll
  for (int c = 0; c < 4; ++c) {
    v4f res = o[c] * inv;
    *(v4f*)(&out[((size_t)(b * SQ + qrow)) * DM + h * HD + 16 * c + 4 * g]) = res;
  }
}

extern "C" void kernel_launch(void* const* d_in, const int* in_sizes, int n_in,
                              void* d_out, int out_size, void* d_ws, size_t ws_size,
                              hipStream_t stream) {
  const float* q = (const float*)d_in[0];
  const float* k = (const float*)d_in[1];
  const float* v = (const float*)d_in[2];
  const float* relk = (const float*)d_in[3];
  const float* relv = (const float*)d_in[4];

  _Float16* Qh = (_Float16*)d_ws;
  _Float16* Kh = Qh + (size_t)NBH * SQ * HD;
  _Float16* Vth = Kh + (size_t)NBH * SQ * HD;

  prep_kernel<<<dim3(NBH * (SQ / 64)), dim3(256), 0, stream>>>(q, k, v, relk, relv, Qh, Kh, Vth);
  attn_kernel<<<dim3(1024), dim3(256), 0, stream>>>(Qh, Kh, Vth, (float*)d_out);
}

// Round 15
// 48.067 us; speedup vs baseline: 1.1376x; 1.0307x over previous
//
#include <hip/hip_runtime.h>

#define SQ 1024
#define DM 1024
#define HD 64
#define NBH 64   // BATCH*NH
#define LOG2E 1.44269504f

typedef __attribute__((ext_vector_type(8))) _Float16 v8h;
typedef __attribute__((ext_vector_type(4))) float v4f;
typedef __attribute__((ext_vector_type(4))) unsigned int v4u;

typedef __attribute__((address_space(3))) void as3_void;
typedef __attribute__((address_space(1))) const void as1_cvoid;

__device__ __forceinline__ v4f mfma_f16(v8h a, v8h b, v4f c) {
  return __builtin_amdgcn_mfma_f32_16x16x32_f16(a, b, c, 0, 0, 0);
}

__device__ __forceinline__ void gload16(const _Float16* g, v8h* l) {
  __builtin_amdgcn_global_load_lds((as1_cvoid*)g, (as3_void*)l, 16, 0, 0);
}

__device__ __forceinline__ float m3(float a, float b, float c) {
  return fmaxf(fmaxf(a, b), c);   // clang fuses to v_max3_f32
}

// Build fp16 K' = (0.125*k + rel_k[s]) * log2e (exp2-domain scores) and
// transposed V'^T where V' = v + rel_v[s]. Q is NOT staged (attn reads fp32
// q directly — it's consumed once, the ws round-trip was pure HBM waste).
// Layouts: Kh: [bh][s][d] (d contiguous, 64), Vth: [bh][d][s] (s contiguous).
__global__ __launch_bounds__(256) void prep_kernel(
    const float* __restrict__ k, const float* __restrict__ v,
    const float* __restrict__ relk, const float* __restrict__ relv,
    _Float16* __restrict__ Kh, _Float16* __restrict__ Vth)
{
  __shared__ float vt[64][65];
  int blk = blockIdx.x;            // bh*16 + stile
  int st = blk & 15;
  int bh = blk >> 4;
  int b = bh >> 4, h = bh & 15;
  int s0 = st * 64;
  int t = (int)threadIdx.x;
  int d = t & 63, sl4 = t >> 6;    // 0..3
  const float scale = 0.125f;

  #pragma unroll
  for (int i = 0; i < 16; ++i) {
    int sl = sl4 + i * 4;
    int s = s0 + sl;
    size_t gidx = ((size_t)(b * SQ + s)) * DM + h * HD + d;
    float kv = (k[gidx] * scale + relk[s * HD + d]) * LOG2E;
    float vv = v[gidx] + relv[s * HD + d];
    Kh[((size_t)(bh * SQ + s)) * HD + d] = (_Float16)kv;
    vt[sl][d] = vv;
  }
  __syncthreads();
  int sl = t & 63, d4 = t >> 6;
  #pragma unroll
  for (int i = 0; i < 16; ++i) {
    int dd = d4 + i * 4;
    Vth[((size_t)(bh * HD + dd)) * SQ + s0 + sl] = (_Float16)vt[sl][dd];
  }
}

// Flash attention fwd (r10/r14 structure — best measured of 8 variants).
// Grid 1024 blocks (XCD-swizzled: 8 XCDs x 128), 4 waves, wave owns ONE
// 16-row q-group. KV tiles of 64, double-buffered (32KB -> 4 blocks/CU),
// staged by global_load_lds (linear LDS dest, XOR swizzle pre-applied on the
// global source granule; same XOR on reads -> conflict-free). 2-phase:
// stage(t+1) issued before compute(t), one __syncthreads per tile.
// QK^T: S^T = K'.Q^T with permuted A-rows -> acc already in PV B-frag layout.
// Scores exp2-domain (LOG2E folded into K' at prep). Q read fp32 direct.
__global__ __launch_bounds__(256) void attn_kernel(
    const float* __restrict__ qf, const _Float16* __restrict__ Kh,
    const _Float16* __restrict__ Vth, float* __restrict__ out)
{
  __shared__ v8h KlG[2 * 512];   // K' tiles  [krow][d]  2 x 8KB
  __shared__ v8h VlG[2 * 512];   // V'^T tiles [d][kcol] 2 x 8KB

  int tid = (int)threadIdx.x;
  int lane = tid & 63, w = tid >> 6;
  int g = lane >> 4, r15 = lane & 15;
  // bijective XCD swizzle: 1024 = 8 XCDs x 128; each XCD gets 8 whole bh (2MB KV < 4MB L2)
  int bid = (int)blockIdx.x;
  int wk = (bid & 7) * 128 + (bid >> 3);
  int bh = wk >> 4, qt = wk & 15;
  int b = bh >> 4, h = bh & 15;
  int q0 = qt * 64 + w * 16;

  // Q B-frag from fp32 global, converted in-register:
  // col = q = r15, contraction d = 8g+j (+32 for aq1)
  const float* qb = qf + ((size_t)(b * SQ + q0 + r15)) * DM + h * HD;
  v4f q00 = *(const v4f*)(qb + 8 * g);
  v4f q01 = *(const v4f*)(qb + 8 * g + 4);
  v4f q10 = *(const v4f*)(qb + 32 + 8 * g);
  v4f q11 = *(const v4f*)(qb + 32 + 8 * g + 4);
  v8h aq0, aq1;
  #pragma unroll
  for (int j = 0; j < 4; ++j) {
    aq0[j] = (_Float16)q00[j];
    aq0[4 + j] = (_Float16)q01[j];
    aq1[j] = (_Float16)q10[j];
    aq1[4 + j] = (_Float16)q11[j];
  }

  const _Float16* kb = Kh + (size_t)bh * SQ * HD;
  const _Float16* vb = Vth + (size_t)bh * HD * SQ;

  // staging precompute: LDS granule G = w*128 + j*64 + lane (linear dest,
  // HW adds lane*16), source granule = (row, gr ^ f(row)) of the logical tile
  size_t kOff[2], vOff[2];
  int ldsG[2];
  #pragma unroll
  for (int j = 0; j < 2; ++j) {
    int G = w * 128 + j * 64 + lane;
    int row = G >> 3, gr = G & 7;
    int fs = (row & 3) | (((row >> 3) & 1) << 2);
    int src = gr ^ fs;
    kOff[j] = (size_t)row * HD + src * 8;
    vOff[j] = (size_t)row * SQ + src * 8;
    ldsG[j] = w * 128 + j * 64;
  }

  v4f o[4];
  #pragma unroll
  for (int c = 0; c < 4; ++c) o[c] = (v4f){0.f, 0.f, 0.f, 0.f};
  float m = -3.0e38f, l = 0.f;

  // K-frag read rows (permuted): k_phys(c,mm) = 32*(c>>1) + 8*(mm>>2) + 4*(c&1) + (mm&3)
  int krow[4];
  #pragma unroll
  for (int c = 0; c < 4; ++c)
    krow[c] = ((c >> 1) << 5) + ((r15 >> 2) << 3) + ((c & 1) << 2) + (r15 & 3);
  int fk = (r15 & 3) | (((r15 >> 2) & 1) << 2);   // f(krow[c]) for all c
  int fv = (r15 & 3) | (((r15 >> 3) & 1) << 2);   // f(16c + r15) for all c

  const int NT = SQ / 64;

  // ---- prologue: stage tile 0 ----
  #pragma unroll
  for (int j = 0; j < 2; ++j) {
    gload16(kb + kOff[j], &KlG[ldsG[j]]);
    gload16(vb + vOff[j], &VlG[ldsG[j]]);
  }
  __syncthreads();   // drains vmcnt(0): tile 0 resident

  for (int t0 = 0; t0 < NT; ++t0) {
    const int cur = t0 & 1;
    // ---- issue next tile's loads into the other buffer ----
    if (t0 < NT - 1) {
      size_t kT = (size_t)(t0 + 1) * 64 * HD;
      size_t vT = (size_t)(t0 + 1) * 64;
      #pragma unroll
      for (int j = 0; j < 2; ++j) {
        gload16(kb + kT + kOff[j], &KlG[(cur ^ 1) * 512 + ldsG[j]]);
        gload16(vb + vT + vOff[j], &VlG[(cur ^ 1) * 512 + ldsG[j]]);
      }
    }

    // ---- S^T = K'.Q^T : s[c][r] = S2[q=r15][k_phys(c,4g+r)] (exp2 domain) ----
    v4f s[4];
    #pragma unroll
    for (int c = 0; c < 4; ++c) {
      v8h kf0 = KlG[cur * 512 + krow[c] * 8 + (g ^ fk)];
      v8h kf1 = KlG[cur * 512 + krow[c] * 8 + ((4 | g) ^ fk)];
      v4f z = (v4f){0.f, 0.f, 0.f, 0.f};
      z = mfma_f16(kf0, aq0, z);
      z = mfma_f16(kf1, aq1, z);
      s[c] = z;
    }

    // ---- exp2-domain online softmax, defer-max (T13, THR=8) ----
    float pa = m3(s[0][0], s[0][1], s[0][2]);
    float pb = m3(s[0][3], s[1][0], s[1][1]);
    float pc = m3(s[1][2], s[1][3], s[2][0]);
    float pd = m3(s[2][1], s[2][2], s[2][3]);
    float pe = m3(s[3][0], s[3][1], s[3][2]);
    float pm = m3(fmaxf(pa, pb), fmaxf(pc, pd), fmaxf(pe, s[3][3]));
    if (!__all(pm - m <= 8.f)) {
      float pmr = fmaxf(pm, __shfl_xor(pm, 16));
      pmr = fmaxf(pmr, __shfl_xor(pmr, 32));
      float mnew = fmaxf(m, pmr);
      float sc = __builtin_amdgcn_exp2f(m - mnew);
      m = mnew;
      l *= sc;
      #pragma unroll
      for (int c = 0; c < 4; ++c) o[c] *= sc;
    }
    float p[16];
    #pragma unroll
    for (int c = 0; c < 4; ++c)
      #pragma unroll
      for (int r = 0; r < 4; ++r) {
        float pv = __builtin_amdgcn_exp2f(s[c][r] - m);
        s[c][r] = pv;
        p[c * 4 + r] = pv;
      }
    float s0 = (p[0] + p[1]) + (p[2] + p[3]);
    float s1 = (p[4] + p[5]) + (p[6] + p[7]);
    float s2 = (p[8] + p[9]) + (p[10] + p[11]);
    float s3 = (p[12] + p[13]) + (p[14] + p[15]);
    l += (s0 + s1) + (s2 + s3);

    // ---- pack P in-lane: acc IS the PV B-frag layout (k-slot 8g+j / 32+8g+j) ----
    v4u w0, w1;
    w0[0] = __builtin_bit_cast(unsigned int, __builtin_amdgcn_cvt_pkrtz(s[0][0], s[0][1]));
    w0[1] = __builtin_bit_cast(unsigned int, __builtin_amdgcn_cvt_pkrtz(s[0][2], s[0][3]));
    w0[2] = __builtin_bit_cast(unsigned int, __builtin_amdgcn_cvt_pkrtz(s[1][0], s[1][1]));
    w0[3] = __builtin_bit_cast(unsigned int, __builtin_amdgcn_cvt_pkrtz(s[1][2], s[1][3]));
    w1[0] = __builtin_bit_cast(unsigned int, __builtin_amdgcn_cvt_pkrtz(s[2][0], s[2][1]));
    w1[1] = __builtin_bit_cast(unsigned int, __builtin_amdgcn_cvt_pkrtz(s[2][2], s[2][3]));
    w1[2] = __builtin_bit_cast(unsigned int, __builtin_amdgcn_cvt_pkrtz(s[3][0], s[3][1]));
    w1[3] = __builtin_bit_cast(unsigned int, __builtin_amdgcn_cvt_pkrtz(s[3][2], s[3][3]));
    v8h pb0 = __builtin_bit_cast(v8h, w0);
    v8h pb1 = __builtin_bit_cast(v8h, w1);

    // ---- O^T += V'^T . P ----
    #pragma unroll
    for (int c = 0; c < 4; ++c) {
      int rv = 16 * c + r15;
      v8h vf0 = VlG[cur * 512 + rv * 8 + (g ^ fv)];
      v8h vf1 = VlG[cur * 512 + rv * 8 + ((4 | g) ^ fv)];
      o[c] = mfma_f16(vf0, pb0, o[c]);
      o[c] = mfma_f16(vf1, pb1, o[c]);
    }

    __syncthreads();   // tile boundary: buffer swap safety + staging drain
  }

  // ---- epilogue: reduce l across k-chunk lanes, normalize, vectorized stores ----
  float lr = l;
  lr += __shfl_xor(lr, 16);
  lr += __shfl_xor(lr, 32);
  float inv = 1.f / lr;
  int qrow = q0 + r15;
  #pragma unroll
  for (int c = 0; c < 4; ++c) {
    v4f res = o[c] * inv;
    *(v4f*)(&out[((size_t)(b * SQ + qrow)) * DM + h * HD + 16 * c + 4 * g]) = res;
  }
}

extern "C" void kernel_launch(void* const* d_in, const int* in_sizes, int n_in,
                              void* d_out, int out_size, void* d_ws, size_t ws_size,
                              hipStream_t stream) {
  const float* q = (const float*)d_in[0];
  const float* k = (const float*)d_in[1];
  const float* v = (const float*)d_in[2];
  const float* relk = (const float*)d_in[3];
  const float* relv = (const float*)d_in[4];

  _Float16* Kh = (_Float16*)d_ws;
  _Float16* Vth = Kh + (size_t)NBH * SQ * HD;

  prep_kernel<<<dim3(NBH * (SQ / 64)), dim3(256), 0, stream>>>(k, v, relk, relv, Kh, Vth);
  attn_kernel<<<dim3(1024), dim3(256), 0, stream>>>(q, Kh, Vth, (float*)d_out);
}